// Round 3
// baseline (212.688 us; speedup 1.0000x reference)
//
#include <hip/hip_runtime.h>

typedef __attribute__((ext_vector_type(8))) short bf16x8;
typedef __attribute__((ext_vector_type(16))) float f32x16;

union BF8 { bf16x8 v; unsigned short u[8]; };

static __device__ __forceinline__ unsigned short f2bf(float f) {
    unsigned u = __float_as_uint(f);
    unsigned r = (u + 0x7FFFu + ((u >> 16) & 1u)) >> 16;   // RNE
    return (unsigned short)r;
}

// ---------------------------------------------------------------------------
// Kernel 1: scatter edges into per-XCD private nibble-count matrices.
// PRIV=true : 8 copies, copy chosen by the WG's physical XCD id, atomics are
//             L2-local (workgroup-scope -> no fabric bypass). Correct for ANY
//             WG->XCD assignment: copy k is only ever touched from XCD k, and
//             the consumer sums all copies.
// PRIV=false: single copy, device-scope atomics (fallback if ws too small).
// Nibble layout: idx = blk*1024 + u*32 + v ; word = idx>>3 ; shift = (idx&7)*4
// ---------------------------------------------------------------------------
template <bool PRIV>
__global__ __launch_bounds__(256) void build_adj(
    const int* __restrict__ row, const int* __restrict__ col,
    unsigned int* __restrict__ adj, int E, int Bwords)
{
    unsigned int* a = adj;
    if (PRIV) {
        unsigned int xcc;
        asm volatile("s_getreg_b32 %0, hwreg(20, 0, 32)" : "=s"(xcc));
        a = adj + (size_t)(xcc & 7) * (unsigned)Bwords;
    }
    const int gid = blockIdx.x * blockDim.x + threadIdx.x;
    const int stride = gridDim.x * blockDim.x;
    const int E4 = E >> 2;
    const int4* row4 = reinterpret_cast<const int4*>(row);
    const int4* col4 = reinterpret_cast<const int4*>(col);

#define EDGE_ADD(r_, c_) do {                                                  \
        int idx = (((r_) >> 5) << 10) + (((r_) & 31) << 5) + ((c_) & 31);      \
        unsigned int add_ = 1u << ((idx & 7) << 2);                            \
        if (PRIV)                                                              \
            __hip_atomic_fetch_add(&a[idx >> 3], add_, __ATOMIC_RELAXED,       \
                                   __HIP_MEMORY_SCOPE_WORKGROUP);              \
        else                                                                   \
            atomicAdd(&a[idx >> 3], add_);                                     \
    } while (0)

    for (int i = gid; i < E4; i += stride) {
        int4 r = row4[i];
        int4 c = col4[i];
        EDGE_ADD(r.x, c.x);
        EDGE_ADD(r.y, c.y);
        EDGE_ADD(r.z, c.z);
        EDGE_ADD(r.w, c.w);
    }
    const int tail = E & 3;
    if (gid < tail) {
        int e = (E4 << 2) + gid;
        EDGE_ADD(row[e], col[e]);
    }
#undef EDGE_ADD
}

// ---------------------------------------------------------------------------
// Kernel 2: one wave per subgraph, all matmuls on MFMA (32x32x16 bf16, K=32).
//   A-frag (assumed): row = l&31, k = 16f + 8*(l>>5) + i   (i = 0..7)
//   B-frag (assumed): col = l&31, k = 16f + 8*(l>>5) + i
//   C/D   (verified): col = l&31, row = (q&3) + 8*(q>>2) + 4*(l>>5)
// A/B k-mapping errors cancel (both operands use the same mapping; dot
// products are k-permutation invariant). Only the C/D mapping must be exact.
// ---------------------------------------------------------------------------
__global__ __launch_bounds__(64, 4) void igmc_kernel(
    const float4* __restrict__ feats4,
    const unsigned int* __restrict__ adj,   // ncopies * Bwords u32 (nibble counts)
    int Bwords, int ncopies,
    const float* __restrict__ W1, const float* __restrict__ B1,
    const float* __restrict__ W2, const float* __restrict__ B2,
    const float* __restrict__ W3, const float* __restrict__ B3,
    const float* __restrict__ lin1W, const float* __restrict__ lin1b,
    const float* __restrict__ lin2W, const float* __restrict__ lin2b,
    float* __restrict__ out)
{
    __shared__ float Hbuf[32 * 33];   // count staging, then layer handoff
    __shared__ float ns[32], nd[32];
    __shared__ float rep[192];        // [user h1|h2|h3 (96) | item h1|h2|h3 (96)]

    const int b = blockIdx.x;
    const int l = threadIdx.x;
    const int h = l >> 5;       // lane half
    const int c = l & 31;       // col (dims) / row (nodes) index, per use

    // ---- sum per-XCD copies (packed nibbles; totals <=15 so no carry) ----
    {
        unsigned int w0 = 0, w1 = 0;
        const unsigned int* cp = adj + b * 128;
        for (int cpy = 0; cpy < ncopies; ++cpy, cp += Bwords) {
            w0 += cp[l];
            w1 += cp[l + 64];
        }
        #pragma unroll
        for (int j = 0; j < 2; ++j) {
            int w = l + 64 * j;           // u32 word index within block (0..127)
            unsigned int ws = j ? w1 : w0;
            int base = w << 3;            // nibble index = u*32 + v
            int u = base >> 5, v0 = base & 31;
            float* p = &Hbuf[u * 33 + v0];
            #pragma unroll
            for (int k = 0; k < 8; ++k) p[k] = (float)((ws >> (4 * k)) & 15u);
        }
    }
    __syncthreads();

    // ---- degrees -> norms ----
    {
        float s = 0.f;
        if (h == 0) {
            #pragma unroll
            for (int v = 0; v < 32; ++v) s += Hbuf[c * 33 + v];
            ns[c] = rsqrtf(fmaxf(s, 1.f));          // out_deg (row sums)
        } else {
            #pragma unroll
            for (int u = 0; u < 32; ++u) s += Hbuf[u * 33 + c];
            nd[c] = rsqrtf(fmaxf(s, 1.f));          // in_deg (col sums)
        }
    }
    __syncthreads();

    // ---- M A-frags: M[r=c][u] = A[u][c] * ns[u] * nd[c] ----
    const float ndr = nd[c];
    BF8 Mf[2];
    #pragma unroll
    for (int f = 0; f < 2; ++f)
        #pragma unroll
        for (int i = 0; i < 8; ++i) {
            int u = 16 * f + 8 * h + i;
            Mf[f].u[i] = f2bf(Hbuf[u * 33 + c] * ns[u] * ndr);
        }

    // ---- weight B-frags + per-lane scalars (global, coalesced, L2-hot) ----
    const float w1r0 = W1[c], w1r1 = W1[32 + c], w1r2 = W1[64 + c], w1r3 = W1[96 + c];
    const float b1r = B1[c], b2r = B2[c], b3r = B3[c];
    BF8 W2f[2], W3f[2];
    #pragma unroll
    for (int f = 0; f < 2; ++f)
        #pragma unroll
        for (int i = 0; i < 8; ++i) {
            int k = 16 * f + 8 * h + i;
            W2f[f].u[i] = f2bf(W2[k * 32 + c]);
            W3f[f].u[i] = f2bf(W3[k * 32 + c]);
        }

    // ---- H0 = X @ W1 (feats one-hot in general form), as B-frags ----
    BF8 H0f[2];
    #pragma unroll
    for (int f = 0; f < 2; ++f)
        #pragma unroll
        for (int i = 0; i < 8; ++i) {
            int u = 16 * f + 8 * h + i;
            float4 x = feats4[b * 32 + u];
            H0f[f].u[i] = f2bf(x.x * w1r0 + x.y * w1r1 + x.z * w1r2 + x.w * w1r3);
        }
    __syncthreads();   // Hbuf (counts) reads done; buffer free for reuse

    f32x16 acc;
    float hreg[16];
    BF8 Xf[2];

    // ==================== Layer 1: H1 = tanh(M@H0 + b1) ====================
    #pragma unroll
    for (int q = 0; q < 16; ++q) acc[q] = 0.f;
    acc = __builtin_amdgcn_mfma_f32_32x32x16_bf16(Mf[0].v, H0f[0].v, acc, 0, 0, 0);
    acc = __builtin_amdgcn_mfma_f32_32x32x16_bf16(Mf[1].v, H0f[1].v, acc, 0, 0, 0);
    #pragma unroll
    for (int q = 0; q < 16; ++q) hreg[q] = tanhf(acc[q] + b1r);
    if (h == 0) { rep[c] = hreg[0]; rep[96 + c] = hreg[8]; }   // rows 0, 16
    #pragma unroll
    for (int q = 0; q < 16; ++q)
        Hbuf[((q & 3) + 8 * (q >> 2) + 4 * h) * 33 + c] = hreg[q];
    __syncthreads();
    #pragma unroll
    for (int f = 0; f < 2; ++f)
        #pragma unroll
        for (int i = 0; i < 8; ++i) {
            int u = 16 * f + 8 * h + i;
            Xf[f].u[i] = f2bf(Hbuf[u * 33 + c]);   // B-frag of H1
        }
    __syncthreads();

    // ==================== Layer 2 ====================
    #pragma unroll
    for (int q = 0; q < 16; ++q) acc[q] = 0.f;
    acc = __builtin_amdgcn_mfma_f32_32x32x16_bf16(Mf[0].v, Xf[0].v, acc, 0, 0, 0);
    acc = __builtin_amdgcn_mfma_f32_32x32x16_bf16(Mf[1].v, Xf[1].v, acc, 0, 0, 0);
    #pragma unroll
    for (int q = 0; q < 16; ++q)   // T2 -> Hbuf (C layout scatter)
        Hbuf[((q & 3) + 8 * (q >> 2) + 4 * h) * 33 + c] = acc[q];
    __syncthreads();
    #pragma unroll
    for (int f = 0; f < 2; ++f)
        #pragma unroll
        for (int i = 0; i < 8; ++i) {
            int k = 16 * f + 8 * h + i;
            Xf[f].u[i] = f2bf(Hbuf[c * 33 + k]);   // A-frag of T2 (transposed read)
        }
    __syncthreads();
    #pragma unroll
    for (int q = 0; q < 16; ++q) acc[q] = 0.f;
    acc = __builtin_amdgcn_mfma_f32_32x32x16_bf16(Xf[0].v, W2f[0].v, acc, 0, 0, 0);
    acc = __builtin_amdgcn_mfma_f32_32x32x16_bf16(Xf[1].v, W2f[1].v, acc, 0, 0, 0);
    #pragma unroll
    for (int q = 0; q < 16; ++q) hreg[q] = tanhf(acc[q] + b2r);
    if (h == 0) { rep[32 + c] = hreg[0]; rep[96 + 32 + c] = hreg[8]; }
    #pragma unroll
    for (int q = 0; q < 16; ++q)
        Hbuf[((q & 3) + 8 * (q >> 2) + 4 * h) * 33 + c] = hreg[q];
    __syncthreads();
    #pragma unroll
    for (int f = 0; f < 2; ++f)
        #pragma unroll
        for (int i = 0; i < 8; ++i) {
            int u = 16 * f + 8 * h + i;
            Xf[f].u[i] = f2bf(Hbuf[u * 33 + c]);   // B-frag of H2
        }
    __syncthreads();

    // ==================== Layer 3 ====================
    #pragma unroll
    for (int q = 0; q < 16; ++q) acc[q] = 0.f;
    acc = __builtin_amdgcn_mfma_f32_32x32x16_bf16(Mf[0].v, Xf[0].v, acc, 0, 0, 0);
    acc = __builtin_amdgcn_mfma_f32_32x32x16_bf16(Mf[1].v, Xf[1].v, acc, 0, 0, 0);
    #pragma unroll
    for (int q = 0; q < 16; ++q)   // T3 -> Hbuf
        Hbuf[((q & 3) + 8 * (q >> 2) + 4 * h) * 33 + c] = acc[q];
    __syncthreads();
    #pragma unroll
    for (int f = 0; f < 2; ++f)
        #pragma unroll
        for (int i = 0; i < 8; ++i) {
            int k = 16 * f + 8 * h + i;
            Xf[f].u[i] = f2bf(Hbuf[c * 33 + k]);   // A-frag of T3
        }
    #pragma unroll
    for (int q = 0; q < 16; ++q) acc[q] = 0.f;
    acc = __builtin_amdgcn_mfma_f32_32x32x16_bf16(Xf[0].v, W3f[0].v, acc, 0, 0, 0);
    acc = __builtin_amdgcn_mfma_f32_32x32x16_bf16(Xf[1].v, W3f[1].v, acc, 0, 0, 0);
    if (h == 0) {
        rep[64 + c]      = tanhf(acc[0] + b3r);   // row 0
        rep[96 + 64 + c] = tanhf(acc[8] + b3r);   // row 16
    }
    __syncthreads();

    // ==================== Head (fp32 VALU) ====================
    {
        float a = 0.f;
        #pragma unroll 8
        for (int k2 = 0; k2 < 96; ++k2) {
            int k = h * 96 + k2;
            a += rep[k] * lin1W[k * 32 + c];
        }
        a += __shfl_xor(a, 32, 64);               // combine half-sums
        a += lin1b[c];
        float hr = fmaxf(a, 0.f);
        float p = hr * lin2W[c];
        #pragma unroll
        for (int off = 16; off > 0; off >>= 1) p += __shfl_xor(p, off, 64);
        if (l == 0) out[b] = p + lin2b[0];
    }
}

// ---------------------------------------------------------------------------
extern "C" void kernel_launch(void* const* d_in, const int* in_sizes, int n_in,
                              void* d_out, int out_size, void* d_ws, size_t ws_size,
                              hipStream_t stream)
{
    const float* feats = (const float*)d_in[0];
    const int*   row   = (const int*)d_in[1];
    const int*   col   = (const int*)d_in[2];
    const float* W1    = (const float*)d_in[3];
    const float* b1    = (const float*)d_in[4];
    const float* W2    = (const float*)d_in[5];
    const float* b2    = (const float*)d_in[6];
    const float* W3    = (const float*)d_in[7];
    const float* b3    = (const float*)d_in[8];
    const float* lin1W = (const float*)d_in[9];
    const float* lin1b = (const float*)d_in[10];
    const float* lin2W = (const float*)d_in[11];
    const float* lin2b = (const float*)d_in[12];

    const int N = in_sizes[0] / 4;
    const int E = in_sizes[1];
    const int B = N / 32;
    const int Bwords = B * 128;               // u32 words per copy (nibble counts)

    const size_t copy_bytes = (size_t)Bwords * 4;   // 4 MB at B=8192
    const int ncopies = (ws_size >= 8 * copy_bytes) ? 8 : 1;

    unsigned int* adj = (unsigned int*)d_ws;
    hipMemsetAsync(d_ws, 0, copy_bytes * (size_t)ncopies, stream);

    int eblocks = (E / 4 + 255) / 256;
    if (eblocks > 2048) eblocks = 2048;
    if (ncopies == 8)
        build_adj<true><<<eblocks, 256, 0, stream>>>(row, col, adj, E, Bwords);
    else
        build_adj<false><<<eblocks, 256, 0, stream>>>(row, col, adj, E, Bwords);

    igmc_kernel<<<B, 64, 0, stream>>>(
        reinterpret_cast<const float4*>(feats),
        adj, Bwords, ncopies,
        W1, b1, W2, b2, W3, b3, lin1W, lin1b, lin2W, lin2b,
        (float*)d_out);
}

// Round 4
// 169.228 us; speedup vs baseline: 1.2568x; 1.2568x over previous
//
#include <hip/hip_runtime.h>

typedef __attribute__((ext_vector_type(8))) short bf16x8;
typedef __attribute__((ext_vector_type(16))) float f32x16;
typedef unsigned int u32;
typedef unsigned short u16;

union BF8 { bf16x8 v; unsigned short u[8]; };

static __device__ __forceinline__ unsigned short f2bf(float f) {
    unsigned u = __float_as_uint(f);
    unsigned r = (u + 0x7FFFu + ((u >> 16) & 1u)) >> 16;   // RNE
    return (unsigned short)r;
}

// ===========================================================================
// Counting-sort pipeline: group edges by subgraph with ZERO device atomics.
// All per-edge atomics are LDS-scope; global traffic is streaming loads plus
// one byte-granular u16 store per edge.
// ===========================================================================

// ---- Pass 1: per-chunk histogram of block ids (LDS atomics) ----
__global__ __launch_bounds__(1024) void hist_kernel(
    const int* __restrict__ row, u32* __restrict__ hist, int E, int CH, int NB)
{
    __shared__ u32 h[8192];
    const int g = blockIdx.x;
    for (int i = threadIdx.x; i < NB; i += 1024) h[i] = 0;
    __syncthreads();
    const int beg = g * CH, end = min(E, beg + CH);
    const int n4 = (end - beg) >> 2;
    const int4* r4 = reinterpret_cast<const int4*>(row + beg);
    for (int i = threadIdx.x; i < n4; i += 1024) {
        int4 r = r4[i];
        atomicAdd(&h[r.x >> 5], 1u);
        atomicAdd(&h[r.y >> 5], 1u);
        atomicAdd(&h[r.z >> 5], 1u);
        atomicAdd(&h[r.w >> 5], 1u);
    }
    for (int i = beg + (n4 << 2) + threadIdx.x; i < end; i += 1024)
        atomicAdd(&h[row[i] >> 5], 1u);
    __syncthreads();
    for (int i = threadIdx.x; i < NB; i += 1024) hist[g * NB + i] = h[i];
}

// ---- Pass 2a: per-block totals ----
__global__ __launch_bounds__(256) void sum_kernel(
    const u32* __restrict__ hist, u32* __restrict__ base, int NB, int G)
{
    const int bin = blockIdx.x * 256 + threadIdx.x;
    u32 s = 0;
    for (int g = 0; g < G; ++g) s += hist[g * NB + bin];
    base[bin] = s;
}

// ---- Pass 2b: exclusive scan of totals (single WG) ----
__global__ __launch_bounds__(256) void scan_kernel(u32* __restrict__ base, int NB, int E)
{
    __shared__ u32 t[8192];
    __shared__ u32 ps[257];
    for (int i = threadIdx.x; i < NB; i += 256) t[i] = base[i];
    __syncthreads();
    const int per = NB / 256;
    const int own = threadIdx.x * per;
    u32 s = 0;
    for (int j = 0; j < per; ++j) s += t[own + j];
    ps[threadIdx.x + 1] = s;
    __syncthreads();
    if (threadIdx.x == 0) {
        ps[0] = 0;
        for (int i = 1; i <= 256; ++i) ps[i] += ps[i - 1];
    }
    __syncthreads();
    u32 cur = ps[threadIdx.x];
    for (int j = 0; j < per; ++j) { u32 v = t[own + j]; t[own + j] = cur; cur += v; }
    __syncthreads();
    for (int i = threadIdx.x; i < NB; i += 256) base[i] = t[i];
    if (threadIdx.x == 0) base[NB] = (u32)E;
}

// ---- Pass 2c: hist[g][bin] -> global start offset of (chunk g, block bin) ----
__global__ __launch_bounds__(256) void start_kernel(
    u32* __restrict__ hist, const u32* __restrict__ base, int NB, int G)
{
    const int bin = blockIdx.x * 256 + threadIdx.x;
    u32 cur = base[bin];
    for (int g = 0; g < G; ++g) { u32 v = hist[g * NB + bin]; hist[g * NB + bin] = cur; cur += v; }
}

// ---- Pass 3: scatter edge codes into per-block runs (LDS cursors) ----
__global__ __launch_bounds__(1024) void scatter_kernel(
    const int* __restrict__ row, const int* __restrict__ col,
    const u32* __restrict__ hist, u16* __restrict__ ebuf, int E, int CH, int NB)
{
    __shared__ u32 cur[8192];
    const int g = blockIdx.x;
    for (int i = threadIdx.x; i < NB; i += 1024) cur[i] = hist[g * NB + i];
    __syncthreads();
    const int beg = g * CH, end = min(E, beg + CH);
    const int n4 = (end - beg) >> 2;
    const int4* r4 = reinterpret_cast<const int4*>(row + beg);
    const int4* c4 = reinterpret_cast<const int4*>(col + beg);
#define SCAT(r_, c_) do {                                        \
        u32 slot = atomicAdd(&cur[(r_) >> 5], 1u);               \
        ebuf[slot] = (u16)((((r_) & 31) << 5) | ((c_) & 31));    \
    } while (0)
    for (int i = threadIdx.x; i < n4; i += 1024) {
        int4 r = r4[i];
        int4 c = c4[i];
        SCAT(r.x, c.x); SCAT(r.y, c.y); SCAT(r.z, c.z); SCAT(r.w, c.w);
    }
    for (int i = beg + (n4 << 2) + threadIdx.x; i < end; i += 1024)
        SCAT(row[i], col[i]);
#undef SCAT
}

// ===========================================================================
// Kernel 4: one wave per subgraph, all matmuls on MFMA (32x32x16 bf16, K=32).
//   A-frag (assumed): row = l&31, k = 16f + 8*(l>>5) + i
//   B-frag (assumed): col = l&31, k = 16f + 8*(l>>5) + i
//   C/D   (verified): col = l&31, row = (q&3) + 8*(q>>2) + 4*(l>>5)
// A/B k-mapping errors cancel (same mapping on both operands; dot products
// are k-permutation invariant). Only the C/D mapping must be exact.
// EDGES=true: counts from sorted edge list. false: nibble-adj fallback.
// ===========================================================================
template <bool EDGES>
__global__ __launch_bounds__(64, 4) void igmc_kernel(
    const float4* __restrict__ feats4,
    const u32* __restrict__ adj,          // fallback: NB*128 u32 nibble counts
    const u16* __restrict__ ebuf,         // sort path: E edge codes
    const u32* __restrict__ base,         // sort path: NB+1 offsets
    const float* __restrict__ W1, const float* __restrict__ B1,
    const float* __restrict__ W2, const float* __restrict__ B2,
    const float* __restrict__ W3, const float* __restrict__ B3,
    const float* __restrict__ lin1W, const float* __restrict__ lin1b,
    const float* __restrict__ lin2W, const float* __restrict__ lin2b,
    float* __restrict__ out)
{
    __shared__ u32 cnt[32 * 33 + 32];   // padded LD=33: conflict-free rows+cols
    __shared__ float Hbuf[32 * 33];     // layer handoff
    __shared__ float ns[32], nd[32];
    __shared__ float rep[192];          // [user h1|h2|h3 | item h1|h2|h3]

    const int b = blockIdx.x;
    const int l = threadIdx.x;
    const int h = l >> 5;
    const int c = l & 31;

    // ---- build counts ----
    if (EDGES) {
        for (int i = l; i < 32 * 33; i += 64) cnt[i] = 0;
        __syncthreads();
        const int beg = (int)base[b], end = (int)base[b + 1];
        for (int i = beg + l; i < end; i += 64) {
            u16 e = ebuf[i];
            atomicAdd(&cnt[(e >> 5) * 33 + (e & 31)], 1u);
        }
    } else {
        const u32* cp = adj + b * 128;
        #pragma unroll
        for (int j = 0; j < 2; ++j) {
            int w = l + 64 * j;             // u32 word 0..127
            u32 ws_ = cp[w];
            int nb0 = w << 3;               // nibble index = u*32 + v
            #pragma unroll
            for (int k = 0; k < 8; ++k) {
                int code = nb0 + k;
                cnt[(code >> 5) * 33 + (code & 31)] = (ws_ >> (4 * k)) & 15u;
            }
        }
    }
    __syncthreads();

    // ---- degrees -> norms ----
    {
        float s = 0.f;
        if (h == 0) {
            #pragma unroll
            for (int v = 0; v < 32; ++v) s += (float)cnt[c * 33 + v];
            ns[c] = rsqrtf(fmaxf(s, 1.f));          // out_deg (row sums)
        } else {
            #pragma unroll
            for (int u = 0; u < 32; ++u) s += (float)cnt[u * 33 + c];
            nd[c] = rsqrtf(fmaxf(s, 1.f));          // in_deg (col sums)
        }
    }
    __syncthreads();

    // ---- M A-frags: M[r=c][u] = A[u][c] * ns[u] * nd[c] ----
    const float ndr = nd[c];
    BF8 Mf[2];
    #pragma unroll
    for (int f = 0; f < 2; ++f)
        #pragma unroll
        for (int i = 0; i < 8; ++i) {
            int u = 16 * f + 8 * h + i;
            Mf[f].u[i] = f2bf((float)cnt[u * 33 + c] * ns[u] * ndr);
        }

    // ---- weight B-frags + per-lane scalars ----
    const float w1r0 = W1[c], w1r1 = W1[32 + c], w1r2 = W1[64 + c], w1r3 = W1[96 + c];
    const float b1r = B1[c], b2r = B2[c], b3r = B3[c];
    BF8 W2f[2], W3f[2];
    #pragma unroll
    for (int f = 0; f < 2; ++f)
        #pragma unroll
        for (int i = 0; i < 8; ++i) {
            int k = 16 * f + 8 * h + i;
            W2f[f].u[i] = f2bf(W2[k * 32 + c]);
            W3f[f].u[i] = f2bf(W3[k * 32 + c]);
        }

    // ---- H0 = X @ W1 as B-frags ----
    BF8 H0f[2];
    #pragma unroll
    for (int f = 0; f < 2; ++f)
        #pragma unroll
        for (int i = 0; i < 8; ++i) {
            int u = 16 * f + 8 * h + i;
            float4 x = feats4[b * 32 + u];
            H0f[f].u[i] = f2bf(x.x * w1r0 + x.y * w1r1 + x.z * w1r2 + x.w * w1r3);
        }

    f32x16 acc;
    float hreg[16];
    BF8 Xf[2];

    // ==================== Layer 1: H1 = tanh(M@H0 + b1) ====================
    #pragma unroll
    for (int q = 0; q < 16; ++q) acc[q] = 0.f;
    acc = __builtin_amdgcn_mfma_f32_32x32x16_bf16(Mf[0].v, H0f[0].v, acc, 0, 0, 0);
    acc = __builtin_amdgcn_mfma_f32_32x32x16_bf16(Mf[1].v, H0f[1].v, acc, 0, 0, 0);
    #pragma unroll
    for (int q = 0; q < 16; ++q) hreg[q] = tanhf(acc[q] + b1r);
    if (h == 0) { rep[c] = hreg[0]; rep[96 + c] = hreg[8]; }   // rows 0, 16
    #pragma unroll
    for (int q = 0; q < 16; ++q)
        Hbuf[((q & 3) + 8 * (q >> 2) + 4 * h) * 33 + c] = hreg[q];
    __syncthreads();
    #pragma unroll
    for (int f = 0; f < 2; ++f)
        #pragma unroll
        for (int i = 0; i < 8; ++i) {
            int u = 16 * f + 8 * h + i;
            Xf[f].u[i] = f2bf(Hbuf[u * 33 + c]);   // B-frag of H1
        }
    __syncthreads();

    // ==================== Layer 2 ====================
    #pragma unroll
    for (int q = 0; q < 16; ++q) acc[q] = 0.f;
    acc = __builtin_amdgcn_mfma_f32_32x32x16_bf16(Mf[0].v, Xf[0].v, acc, 0, 0, 0);
    acc = __builtin_amdgcn_mfma_f32_32x32x16_bf16(Mf[1].v, Xf[1].v, acc, 0, 0, 0);
    #pragma unroll
    for (int q = 0; q < 16; ++q)   // T2 -> Hbuf (C layout scatter)
        Hbuf[((q & 3) + 8 * (q >> 2) + 4 * h) * 33 + c] = acc[q];
    __syncthreads();
    #pragma unroll
    for (int f = 0; f < 2; ++f)
        #pragma unroll
        for (int i = 0; i < 8; ++i) {
            int k = 16 * f + 8 * h + i;
            Xf[f].u[i] = f2bf(Hbuf[c * 33 + k]);   // A-frag of T2 (transposed)
        }
    __syncthreads();
    #pragma unroll
    for (int q = 0; q < 16; ++q) acc[q] = 0.f;
    acc = __builtin_amdgcn_mfma_f32_32x32x16_bf16(Xf[0].v, W2f[0].v, acc, 0, 0, 0);
    acc = __builtin_amdgcn_mfma_f32_32x32x16_bf16(Xf[1].v, W2f[1].v, acc, 0, 0, 0);
    #pragma unroll
    for (int q = 0; q < 16; ++q) hreg[q] = tanhf(acc[q] + b2r);
    if (h == 0) { rep[32 + c] = hreg[0]; rep[96 + 32 + c] = hreg[8]; }
    #pragma unroll
    for (int q = 0; q < 16; ++q)
        Hbuf[((q & 3) + 8 * (q >> 2) + 4 * h) * 33 + c] = hreg[q];
    __syncthreads();
    #pragma unroll
    for (int f = 0; f < 2; ++f)
        #pragma unroll
        for (int i = 0; i < 8; ++i) {
            int u = 16 * f + 8 * h + i;
            Xf[f].u[i] = f2bf(Hbuf[u * 33 + c]);   // B-frag of H2
        }
    __syncthreads();

    // ==================== Layer 3 ====================
    #pragma unroll
    for (int q = 0; q < 16; ++q) acc[q] = 0.f;
    acc = __builtin_amdgcn_mfma_f32_32x32x16_bf16(Mf[0].v, Xf[0].v, acc, 0, 0, 0);
    acc = __builtin_amdgcn_mfma_f32_32x32x16_bf16(Mf[1].v, Xf[1].v, acc, 0, 0, 0);
    #pragma unroll
    for (int q = 0; q < 16; ++q)   // T3 -> Hbuf
        Hbuf[((q & 3) + 8 * (q >> 2) + 4 * h) * 33 + c] = acc[q];
    __syncthreads();
    #pragma unroll
    for (int f = 0; f < 2; ++f)
        #pragma unroll
        for (int i = 0; i < 8; ++i) {
            int k = 16 * f + 8 * h + i;
            Xf[f].u[i] = f2bf(Hbuf[c * 33 + k]);   // A-frag of T3
        }
    #pragma unroll
    for (int q = 0; q < 16; ++q) acc[q] = 0.f;
    acc = __builtin_amdgcn_mfma_f32_32x32x16_bf16(Xf[0].v, W3f[0].v, acc, 0, 0, 0);
    acc = __builtin_amdgcn_mfma_f32_32x32x16_bf16(Xf[1].v, W3f[1].v, acc, 0, 0, 0);
    if (h == 0) {
        rep[64 + c]      = tanhf(acc[0] + b3r);   // row 0
        rep[96 + 64 + c] = tanhf(acc[8] + b3r);   // row 16
    }
    __syncthreads();

    // ==================== Head (fp32 VALU) ====================
    {
        float a = 0.f;
        #pragma unroll 8
        for (int k2 = 0; k2 < 96; ++k2) {
            int k = h * 96 + k2;
            a += rep[k] * lin1W[k * 32 + c];
        }
        a += __shfl_xor(a, 32, 64);
        a += lin1b[c];
        float hr = fmaxf(a, 0.f);
        float p = hr * lin2W[c];
        #pragma unroll
        for (int off = 16; off > 0; off >>= 1) p += __shfl_xor(p, off, 64);
        if (l == 0) out[b] = p + lin2b[0];
    }
}

// ---- fallback: single-copy nibble adjacency, device atomics ----
__global__ __launch_bounds__(256) void build_adj(
    const int* __restrict__ row, const int* __restrict__ col,
    u32* __restrict__ adj, int E)
{
    const int gid = blockIdx.x * blockDim.x + threadIdx.x;
    const int stride = gridDim.x * blockDim.x;
    const int E4 = E >> 2;
    const int4* row4 = reinterpret_cast<const int4*>(row);
    const int4* col4 = reinterpret_cast<const int4*>(col);
#define EDGE_ADD(r_, c_) do {                                                  \
        int idx = (((r_) >> 5) << 10) + (((r_) & 31) << 5) + ((c_) & 31);      \
        atomicAdd(&adj[idx >> 3], 1u << ((idx & 7) << 2));                     \
    } while (0)
    for (int i = gid; i < E4; i += stride) {
        int4 r = row4[i];
        int4 c = col4[i];
        EDGE_ADD(r.x, c.x); EDGE_ADD(r.y, c.y);
        EDGE_ADD(r.z, c.z); EDGE_ADD(r.w, c.w);
    }
    const int tail = E & 3;
    if (gid < tail) {
        int e = (E4 << 2) + gid;
        EDGE_ADD(row[e], col[e]);
    }
#undef EDGE_ADD
}

// ---------------------------------------------------------------------------
extern "C" void kernel_launch(void* const* d_in, const int* in_sizes, int n_in,
                              void* d_out, int out_size, void* d_ws, size_t ws_size,
                              hipStream_t stream)
{
    const float* feats = (const float*)d_in[0];
    const int*   row   = (const int*)d_in[1];
    const int*   col   = (const int*)d_in[2];
    const float* W1    = (const float*)d_in[3];
    const float* b1    = (const float*)d_in[4];
    const float* W2    = (const float*)d_in[5];
    const float* b2    = (const float*)d_in[6];
    const float* W3    = (const float*)d_in[7];
    const float* b3    = (const float*)d_in[8];
    const float* lin1W = (const float*)d_in[9];
    const float* lin1b = (const float*)d_in[10];
    const float* lin2W = (const float*)d_in[11];
    const float* lin2b = (const float*)d_in[12];

    const int N = in_sizes[0] / 4;
    const int E = in_sizes[1];
    const int NB = N / 32;

    const int G = 64;
    const int CH = (((E + G - 1) / G) + 3) & ~3;
    const size_t off_hist = ((size_t)(NB + 1) * 4 + 255) & ~(size_t)255;
    const size_t off_ebuf = (off_hist + (size_t)G * NB * 4 + 255) & ~(size_t)255;
    const size_t need = off_ebuf + (size_t)E * 2;
    const bool use_sort = (ws_size >= need) && (NB <= 8192) && (NB % 256 == 0);

    if (use_sort) {
        u32* base = (u32*)d_ws;
        u32* hist = (u32*)((char*)d_ws + off_hist);
        u16* ebuf = (u16*)((char*)d_ws + off_ebuf);
        hist_kernel<<<G, 1024, 0, stream>>>(row, hist, E, CH, NB);
        sum_kernel<<<NB / 256, 256, 0, stream>>>(hist, base, NB, G);
        scan_kernel<<<1, 256, 0, stream>>>(base, NB, E);
        start_kernel<<<NB / 256, 256, 0, stream>>>(hist, base, NB, G);
        scatter_kernel<<<G, 1024, 0, stream>>>(row, col, hist, ebuf, E, CH, NB);
        igmc_kernel<true><<<NB, 64, 0, stream>>>(
            reinterpret_cast<const float4*>(feats),
            nullptr, ebuf, base,
            W1, b1, W2, b2, W3, b3, lin1W, lin1b, lin2W, lin2b,
            (float*)d_out);
    } else {
        u32* adj = (u32*)d_ws;
        hipMemsetAsync(d_ws, 0, (size_t)NB * 512, stream);
        int eblocks = (E / 4 + 255) / 256;
        if (eblocks > 2048) eblocks = 2048;
        build_adj<<<eblocks, 256, 0, stream>>>(row, col, adj, E);
        igmc_kernel<false><<<NB, 64, 0, stream>>>(
            reinterpret_cast<const float4*>(feats),
            adj, nullptr, nullptr,
            W1, b1, W2, b2, W3, b3, lin1W, lin1b, lin2W, lin2b,
            (float*)d_out);
    }
}

// Round 5
// 85.775 us; speedup vs baseline: 2.4796x; 1.9729x over previous
//
#include <hip/hip_runtime.h>

typedef __attribute__((ext_vector_type(8))) short bf16x8;
typedef __attribute__((ext_vector_type(16))) float f32x16;
typedef unsigned int u32;
typedef unsigned short u16;

#define GA   256      // chunks (hist/scatter WGs)
#define NBKT 128      // buckets; bucket = 64 consecutive blocks
#define BATCH 4096    // edges per scatter batch

union BF8 { bf16x8 v; unsigned short u[8]; };

static __device__ __forceinline__ unsigned short f2bf(float f) {
    unsigned u = __float_as_uint(f);
    unsigned r = (u + 0x7FFFu + ((u >> 16) & 1u)) >> 16;   // RNE
    return (unsigned short)r;
}

// ===========================================================================
// Pass 1: per-chunk histogram of buckets (LDS atomics only)
// ===========================================================================
__global__ __launch_bounds__(256) void histA(
    const int* __restrict__ row, u32* __restrict__ hist, int E, int CH)
{
    __shared__ u32 h[NBKT];
    const int t = threadIdx.x, g = blockIdx.x;
    if (t < NBKT) h[t] = 0;
    __syncthreads();
    const int beg = g * CH, end = min(E, beg + CH);
    const int n4 = (end - beg) >> 2;
    const int4* r4 = reinterpret_cast<const int4*>(row + beg);
    for (int i = t; i < n4; i += 256) {
        int4 r = r4[i];
        atomicAdd(&h[r.x >> 11], 1u);
        atomicAdd(&h[r.y >> 11], 1u);
        atomicAdd(&h[r.z >> 11], 1u);
        atomicAdd(&h[r.w >> 11], 1u);
    }
    __syncthreads();
    if (t < NBKT) hist[g * NBKT + t] = h[t];
}

// ===========================================================================
// Pass 2: bucket totals, exclusive scan, rewrite hist as (chunk,bucket) cursors
// ===========================================================================
__global__ __launch_bounds__(128) void scanA(
    u32* __restrict__ hist, u32* __restrict__ bb, int E)
{
    __shared__ u32 w0tot;
    const int t = threadIdx.x;            // t = bucket (0..127)
    u32 tot = 0;
    for (int w = 0; w < GA; ++w) tot += hist[w * NBKT + t];
    u32 s = tot;
    #pragma unroll
    for (int off = 1; off < 64; off <<= 1) {
        u32 u_ = __shfl_up(s, off);
        if ((t & 63) >= off) s += u_;
    }
    if (t == 63) w0tot = s;
    __syncthreads();
    const u32 excl = s - tot + ((t >= 64) ? w0tot : 0);
    bb[t] = excl;
    if (t == 127) bb[128] = excl + tot;   // == E
    u32 run = excl;
    for (int w = 0; w < GA; ++w) {
        u32 v = hist[w * NBKT + t];
        hist[w * NBKT + t] = run;
        run += v;
    }
}

// ===========================================================================
// Pass 3: batched compaction scatter — all global writes are contiguous runs
// code u32 = blk(13)<<10 | (r&31)<<5 | (c&31); bucket = code>>16; u16 stored.
// ===========================================================================
__global__ __launch_bounds__(256) void scatterA(
    const int* __restrict__ row, const int* __restrict__ col,
    const u32* __restrict__ hist, u16* __restrict__ ebuf, int E, int CH)
{
    __shared__ u32 cur[NBKT], bcnt[NBKT], bpos[NBKT];
    __shared__ u32 stage[BATCH];
    __shared__ u32 w0tot;
    const int t = threadIdx.x, g = blockIdx.x;
    if (t < NBKT) cur[t] = hist[g * NBKT + t];
    const int beg = g * CH, end = min(E, beg + CH);
    const int nE = end - beg;                       // multiple of 4
    const int4* r4 = reinterpret_cast<const int4*>(row + beg);
    const int4* c4 = reinterpret_cast<const int4*>(col + beg);
    const int niter = (nE + BATCH - 1) / BATCH;

    for (int it = 0; it < niter; ++it) {
        if (t < NBKT) bcnt[t] = 0;
        __syncthreads();

        u32 code[16];
        int rank[16];
        #pragma unroll
        for (int kv = 0; kv < 4; ++kv) {
            int i4 = it * (BATCH / 4) + kv * 256 + t;
            bool v = (i4 * 4) < nE;
            int4 r = v ? r4[i4] : make_int4(0, 0, 0, 0);
            int4 c = v ? c4[i4] : make_int4(0, 0, 0, 0);
            int k0 = kv * 4;
            code[k0 + 0] = v ? (u32)(((r.x >> 5) << 10) | ((r.x & 31) << 5) | (c.x & 31)) : ~0u;
            code[k0 + 1] = v ? (u32)(((r.y >> 5) << 10) | ((r.y & 31) << 5) | (c.y & 31)) : ~0u;
            code[k0 + 2] = v ? (u32)(((r.z >> 5) << 10) | ((r.z & 31) << 5) | (c.z & 31)) : ~0u;
            code[k0 + 3] = v ? (u32)(((r.w >> 5) << 10) | ((r.w & 31) << 5) | (c.w & 31)) : ~0u;
        }
        #pragma unroll
        for (int k = 0; k < 16; ++k)
            rank[k] = (code[k] != ~0u) ? (int)atomicAdd(&bcnt[code[k] >> 16], 1u) : 0;
        __syncthreads();

        // exclusive scan of bcnt over 128 buckets (2-wave shfl scan + fixup)
        u32 v_ = (t < NBKT) ? bcnt[t] : 0;
        u32 s = v_;
        #pragma unroll
        for (int off = 1; off < 64; off <<= 1) {
            u32 u_ = __shfl_up(s, off);
            if ((t & 63) >= off) s += u_;
        }
        if (t == 63) w0tot = s;
        __syncthreads();
        if (t < NBKT) bpos[t] = s - v_ + ((t >= 64) ? w0tot : 0);
        __syncthreads();

        #pragma unroll
        for (int k = 0; k < 16; ++k)
            if (code[k] != ~0u) stage[bpos[code[k] >> 16] + rank[k]] = code[k];
        __syncthreads();

        const int total = (int)(bpos[NBKT - 1] + bcnt[NBKT - 1]);
        for (int j = t; j < total; j += 256) {
            u32 cv = stage[j];
            u32 b = cv >> 16;
            ebuf[cur[b] + (j - bpos[b])] = (u16)cv;   // contiguous per-bucket runs
        }
        __syncthreads();
        if (t < NBKT) cur[t] += bcnt[t];
        __syncthreads();
    }
}

// ===========================================================================
// Pass 4: per-bucket nibble-count adjacency, built in LDS, flushed coalesced.
// local code (u16) = blkLocal(6)<<10 | r<<5 | c ; adj word = blk*128 + rc>>3
// ===========================================================================
__global__ __launch_bounds__(1024) void countB(
    const u16* __restrict__ ebuf, const u32* __restrict__ bb, u32* __restrict__ adj)
{
    __shared__ u32 nib[8192];   // 64 blocks x 128 words (nibble counts)
    const int t = threadIdx.x, w = blockIdx.x;
    #pragma unroll
    for (int i = t; i < 8192; i += 1024) nib[i] = 0;
    __syncthreads();
    const int s = (int)bb[w], e = (int)bb[w + 1];
    for (int i = s + t; i < e; i += 1024) {
        u32 lc = ebuf[i];
        atomicAdd(&nib[lc >> 3], 1u << ((lc & 7) << 2));
    }
    __syncthreads();
    u32* dst = adj + (size_t)w * 8192;
    #pragma unroll
    for (int i = t; i < 8192; i += 1024) dst[i] = nib[i];
}

// ===========================================================================
// Kernel 5: one wave per subgraph, all matmuls on MFMA (32x32x16 bf16, K=32).
//   A-frag (assumed): row = l&31, k = 16f + 8*(l>>5) + i
//   B-frag (assumed): col = l&31, k = 16f + 8*(l>>5) + i
//   C/D   (verified): col = l&31, row = (q&3) + 8*(q>>2) + 4*(l>>5)
// A/B k-mapping errors cancel (same mapping both operands). C/D must be exact.
// ===========================================================================
__global__ __launch_bounds__(64, 4) void igmc_kernel(
    const float4* __restrict__ feats4,
    const u32* __restrict__ adj,          // NB*128 u32 nibble counts
    const float* __restrict__ W1, const float* __restrict__ B1,
    const float* __restrict__ W2, const float* __restrict__ B2,
    const float* __restrict__ W3, const float* __restrict__ B3,
    const float* __restrict__ lin1W, const float* __restrict__ lin1b,
    const float* __restrict__ lin2W, const float* __restrict__ lin2b,
    float* __restrict__ out)
{
    __shared__ u32 cnt[32 * 33 + 32];
    __shared__ float Hbuf[32 * 33];
    __shared__ float ns[32], nd[32];
    __shared__ float rep[192];

    const int b = blockIdx.x;
    const int l = threadIdx.x;
    const int h = l >> 5;
    const int c = l & 31;

    // ---- unpack nibble counts ----
    {
        const u32* cp = adj + b * 128;
        #pragma unroll
        for (int j = 0; j < 2; ++j) {
            int w = l + 64 * j;
            u32 ws_ = cp[w];
            int nb0 = w << 3;
            #pragma unroll
            for (int k = 0; k < 8; ++k) {
                int code = nb0 + k;
                cnt[(code >> 5) * 33 + (code & 31)] = (ws_ >> (4 * k)) & 15u;
            }
        }
    }
    __syncthreads();

    // ---- degrees -> norms ----
    {
        float s = 0.f;
        if (h == 0) {
            #pragma unroll
            for (int v = 0; v < 32; ++v) s += (float)cnt[c * 33 + v];
            ns[c] = rsqrtf(fmaxf(s, 1.f));
        } else {
            #pragma unroll
            for (int u = 0; u < 32; ++u) s += (float)cnt[u * 33 + c];
            nd[c] = rsqrtf(fmaxf(s, 1.f));
        }
    }
    __syncthreads();

    // ---- M A-frags: M[r=c][u] = A[u][c] * ns[u] * nd[c] ----
    const float ndr = nd[c];
    BF8 Mf[2];
    #pragma unroll
    for (int f = 0; f < 2; ++f)
        #pragma unroll
        for (int i = 0; i < 8; ++i) {
            int u = 16 * f + 8 * h + i;
            Mf[f].u[i] = f2bf((float)cnt[u * 33 + c] * ns[u] * ndr);
        }

    const float w1r0 = W1[c], w1r1 = W1[32 + c], w1r2 = W1[64 + c], w1r3 = W1[96 + c];
    const float b1r = B1[c], b2r = B2[c], b3r = B3[c];
    BF8 W2f[2], W3f[2];
    #pragma unroll
    for (int f = 0; f < 2; ++f)
        #pragma unroll
        for (int i = 0; i < 8; ++i) {
            int k = 16 * f + 8 * h + i;
            W2f[f].u[i] = f2bf(W2[k * 32 + c]);
            W3f[f].u[i] = f2bf(W3[k * 32 + c]);
        }

    BF8 H0f[2];
    #pragma unroll
    for (int f = 0; f < 2; ++f)
        #pragma unroll
        for (int i = 0; i < 8; ++i) {
            int u = 16 * f + 8 * h + i;
            float4 x = feats4[b * 32 + u];
            H0f[f].u[i] = f2bf(x.x * w1r0 + x.y * w1r1 + x.z * w1r2 + x.w * w1r3);
        }

    f32x16 acc;
    float hreg[16];
    BF8 Xf[2];

    // ==================== Layer 1: H1 = tanh(M@H0 + b1) ====================
    #pragma unroll
    for (int q = 0; q < 16; ++q) acc[q] = 0.f;
    acc = __builtin_amdgcn_mfma_f32_32x32x16_bf16(Mf[0].v, H0f[0].v, acc, 0, 0, 0);
    acc = __builtin_amdgcn_mfma_f32_32x32x16_bf16(Mf[1].v, H0f[1].v, acc, 0, 0, 0);
    #pragma unroll
    for (int q = 0; q < 16; ++q) hreg[q] = tanhf(acc[q] + b1r);
    if (h == 0) { rep[c] = hreg[0]; rep[96 + c] = hreg[8]; }
    #pragma unroll
    for (int q = 0; q < 16; ++q)
        Hbuf[((q & 3) + 8 * (q >> 2) + 4 * h) * 33 + c] = hreg[q];
    __syncthreads();
    #pragma unroll
    for (int f = 0; f < 2; ++f)
        #pragma unroll
        for (int i = 0; i < 8; ++i) {
            int u = 16 * f + 8 * h + i;
            Xf[f].u[i] = f2bf(Hbuf[u * 33 + c]);   // B-frag of H1
        }
    __syncthreads();

    // ==================== Layer 2 ====================
    #pragma unroll
    for (int q = 0; q < 16; ++q) acc[q] = 0.f;
    acc = __builtin_amdgcn_mfma_f32_32x32x16_bf16(Mf[0].v, Xf[0].v, acc, 0, 0, 0);
    acc = __builtin_amdgcn_mfma_f32_32x32x16_bf16(Mf[1].v, Xf[1].v, acc, 0, 0, 0);
    #pragma unroll
    for (int q = 0; q < 16; ++q)
        Hbuf[((q & 3) + 8 * (q >> 2) + 4 * h) * 33 + c] = acc[q];
    __syncthreads();
    #pragma unroll
    for (int f = 0; f < 2; ++f)
        #pragma unroll
        for (int i = 0; i < 8; ++i) {
            int k = 16 * f + 8 * h + i;
            Xf[f].u[i] = f2bf(Hbuf[c * 33 + k]);   // A-frag of T2
        }
    __syncthreads();
    #pragma unroll
    for (int q = 0; q < 16; ++q) acc[q] = 0.f;
    acc = __builtin_amdgcn_mfma_f32_32x32x16_bf16(Xf[0].v, W2f[0].v, acc, 0, 0, 0);
    acc = __builtin_amdgcn_mfma_f32_32x32x16_bf16(Xf[1].v, W2f[1].v, acc, 0, 0, 0);
    #pragma unroll
    for (int q = 0; q < 16; ++q) hreg[q] = tanhf(acc[q] + b2r);
    if (h == 0) { rep[32 + c] = hreg[0]; rep[96 + 32 + c] = hreg[8]; }
    #pragma unroll
    for (int q = 0; q < 16; ++q)
        Hbuf[((q & 3) + 8 * (q >> 2) + 4 * h) * 33 + c] = hreg[q];
    __syncthreads();
    #pragma unroll
    for (int f = 0; f < 2; ++f)
        #pragma unroll
        for (int i = 0; i < 8; ++i) {
            int u = 16 * f + 8 * h + i;
            Xf[f].u[i] = f2bf(Hbuf[u * 33 + c]);   // B-frag of H2
        }
    __syncthreads();

    // ==================== Layer 3 ====================
    #pragma unroll
    for (int q = 0; q < 16; ++q) acc[q] = 0.f;
    acc = __builtin_amdgcn_mfma_f32_32x32x16_bf16(Mf[0].v, Xf[0].v, acc, 0, 0, 0);
    acc = __builtin_amdgcn_mfma_f32_32x32x16_bf16(Mf[1].v, Xf[1].v, acc, 0, 0, 0);
    #pragma unroll
    for (int q = 0; q < 16; ++q)
        Hbuf[((q & 3) + 8 * (q >> 2) + 4 * h) * 33 + c] = acc[q];
    __syncthreads();
    #pragma unroll
    for (int f = 0; f < 2; ++f)
        #pragma unroll
        for (int i = 0; i < 8; ++i) {
            int k = 16 * f + 8 * h + i;
            Xf[f].u[i] = f2bf(Hbuf[c * 33 + k]);   // A-frag of T3
        }
    #pragma unroll
    for (int q = 0; q < 16; ++q) acc[q] = 0.f;
    acc = __builtin_amdgcn_mfma_f32_32x32x16_bf16(Xf[0].v, W3f[0].v, acc, 0, 0, 0);
    acc = __builtin_amdgcn_mfma_f32_32x32x16_bf16(Xf[1].v, W3f[1].v, acc, 0, 0, 0);
    if (h == 0) {
        rep[64 + c]      = tanhf(acc[0] + b3r);
        rep[96 + 64 + c] = tanhf(acc[8] + b3r);
    }
    __syncthreads();

    // ==================== Head (fp32 VALU) ====================
    {
        float a = 0.f;
        #pragma unroll 8
        for (int k2 = 0; k2 < 96; ++k2) {
            int k = h * 96 + k2;
            a += rep[k] * lin1W[k * 32 + c];
        }
        a += __shfl_xor(a, 32, 64);
        a += lin1b[c];
        float hr = fmaxf(a, 0.f);
        float p = hr * lin2W[c];
        #pragma unroll
        for (int off = 16; off > 0; off >>= 1) p += __shfl_xor(p, off, 64);
        if (l == 0) out[b] = p + lin2b[0];
    }
}

// ---- fallback: single-copy nibble adjacency, device atomics (correct, slow) ----
__global__ __launch_bounds__(256) void build_adj(
    const int* __restrict__ row, const int* __restrict__ col,
    u32* __restrict__ adj, int E)
{
    const int gid = blockIdx.x * blockDim.x + threadIdx.x;
    const int stride = gridDim.x * blockDim.x;
    for (int e = gid; e < E; e += stride) {
        int r = row[e], c = col[e];
        int idx = ((r >> 5) << 10) + ((r & 31) << 5) + (c & 31);
        atomicAdd(&adj[idx >> 3], 1u << ((idx & 7) << 2));
    }
}

// ---------------------------------------------------------------------------
extern "C" void kernel_launch(void* const* d_in, const int* in_sizes, int n_in,
                              void* d_out, int out_size, void* d_ws, size_t ws_size,
                              hipStream_t stream)
{
    const float* feats = (const float*)d_in[0];
    const int*   row   = (const int*)d_in[1];
    const int*   col   = (const int*)d_in[2];
    const float* W1    = (const float*)d_in[3];
    const float* b1    = (const float*)d_in[4];
    const float* W2    = (const float*)d_in[5];
    const float* b2    = (const float*)d_in[6];
    const float* W3    = (const float*)d_in[7];
    const float* b3    = (const float*)d_in[8];
    const float* lin1W = (const float*)d_in[9];
    const float* lin1b = (const float*)d_in[10];
    const float* lin2W = (const float*)d_in[11];
    const float* lin2b = (const float*)d_in[12];

    const int N = in_sizes[0] / 4;
    const int E = in_sizes[1];
    const int NB = N / 32;

    const int CH = (((E + GA - 1) / GA) + 3) & ~3;
    const size_t off_hist = 1024;                                  // bb: 129 u32
    const size_t off_ebuf = off_hist + (size_t)GA * NBKT * 4;      // hist 128 KB
    const size_t off_adj  = (off_ebuf + (size_t)E * 2 + 255) & ~(size_t)255;
    const size_t need     = off_adj + (size_t)NB * 512;
    const bool fast = (ws_size >= need) && (NB == 8192) && ((E & 3) == 0);

    if (fast) {
        u32* bb   = (u32*)d_ws;
        u32* hist = (u32*)((char*)d_ws + off_hist);
        u16* ebuf = (u16*)((char*)d_ws + off_ebuf);
        u32* adj  = (u32*)((char*)d_ws + off_adj);
        histA<<<GA, 256, 0, stream>>>(row, hist, E, CH);
        scanA<<<1, 128, 0, stream>>>(hist, bb, E);
        scatterA<<<GA, 256, 0, stream>>>(row, col, hist, ebuf, E, CH);
        countB<<<NBKT, 1024, 0, stream>>>(ebuf, bb, adj);
        igmc_kernel<<<NB, 64, 0, stream>>>(
            reinterpret_cast<const float4*>(feats), adj,
            W1, b1, W2, b2, W3, b3, lin1W, lin1b, lin2W, lin2b,
            (float*)d_out);
    } else {
        u32* adj = (u32*)d_ws;
        hipMemsetAsync(d_ws, 0, (size_t)NB * 512, stream);
        int eblocks = (E + 255) / 256;
        if (eblocks > 2048) eblocks = 2048;
        build_adj<<<eblocks, 256, 0, stream>>>(row, col, adj, E);
        igmc_kernel<<<NB, 64, 0, stream>>>(
            reinterpret_cast<const float4*>(feats), adj,
            W1, b1, W2, b2, W3, b3, lin1W, lin1b, lin2W, lin2b,
            (float*)d_out);
    }
}

// Round 6
// 83.103 us; speedup vs baseline: 2.5593x; 1.0322x over previous
//
#include <hip/hip_runtime.h>

typedef __attribute__((ext_vector_type(8))) short bf16x8;
typedef __attribute__((ext_vector_type(16))) float f32x16;
typedef unsigned int u32;
typedef unsigned short u16;

#define GA   256      // chunks (hist/scatter WGs)
#define NBKT 128      // buckets; bucket = 64 consecutive blocks
#define BATCH 4096    // edges per scatter batch

union BF8 { bf16x8 v; u16 u[8]; u32 w[4]; };

static __device__ __forceinline__ u16 f2bf(float f) {
    u32 u = __float_as_uint(f);
    return (u16)((u + 0x7FFFu + ((u >> 16) & 1u)) >> 16);   // RNE
}
static __device__ __forceinline__ u32 f2bf2(float lo, float hi) {
    return (u32)f2bf(lo) | ((u32)f2bf(hi) << 16);
}

// ===========================================================================
// Pass 1: per-chunk histogram of buckets (LDS atomics only)
// ===========================================================================
__global__ __launch_bounds__(256) void histA(
    const int* __restrict__ row, u32* __restrict__ hist, int E, int CH)
{
    __shared__ u32 h[NBKT];
    const int t = threadIdx.x, g = blockIdx.x;
    if (t < NBKT) h[t] = 0;
    __syncthreads();
    const int beg = g * CH, end = min(E, beg + CH);
    const int n4 = (end - beg) >> 2;
    const int4* r4 = reinterpret_cast<const int4*>(row + beg);
    for (int i = t; i < n4; i += 256) {
        int4 r = r4[i];
        atomicAdd(&h[r.x >> 11], 1u);
        atomicAdd(&h[r.y >> 11], 1u);
        atomicAdd(&h[r.z >> 11], 1u);
        atomicAdd(&h[r.w >> 11], 1u);
    }
    __syncthreads();
    if (t < NBKT) hist[g * NBKT + t] = h[t];
}

// ===========================================================================
// Pass 2: bucket totals, exclusive scan, rewrite hist as (chunk,bucket) cursors
// ===========================================================================
__global__ __launch_bounds__(128) void scanA(
    u32* __restrict__ hist, u32* __restrict__ bb, int E)
{
    __shared__ u32 w0tot;
    const int t = threadIdx.x;            // t = bucket (0..127)
    u32 tot = 0;
    for (int w = 0; w < GA; ++w) tot += hist[w * NBKT + t];
    u32 s = tot;
    #pragma unroll
    for (int off = 1; off < 64; off <<= 1) {
        u32 u_ = __shfl_up(s, off);
        if ((t & 63) >= off) s += u_;
    }
    if (t == 63) w0tot = s;
    __syncthreads();
    const u32 excl = s - tot + ((t >= 64) ? w0tot : 0);
    bb[t] = excl;
    if (t == 127) bb[128] = excl + tot;   // == E
    u32 run = excl;
    for (int w = 0; w < GA; ++w) {
        u32 v = hist[w * NBKT + t];
        hist[w * NBKT + t] = run;
        run += v;
    }
}

// ===========================================================================
// Pass 3: batched compaction scatter — all global writes are contiguous runs
// ===========================================================================
__global__ __launch_bounds__(256) void scatterA(
    const int* __restrict__ row, const int* __restrict__ col,
    const u32* __restrict__ hist, u16* __restrict__ ebuf, int E, int CH)
{
    __shared__ u32 cur[NBKT], bcnt[NBKT], bpos[NBKT];
    __shared__ u32 stage[BATCH];
    __shared__ u32 w0tot;
    const int t = threadIdx.x, g = blockIdx.x;
    if (t < NBKT) cur[t] = hist[g * NBKT + t];
    const int beg = g * CH, end = min(E, beg + CH);
    const int nE = end - beg;                       // multiple of 4
    const int4* r4 = reinterpret_cast<const int4*>(row + beg);
    const int4* c4 = reinterpret_cast<const int4*>(col + beg);
    const int niter = (nE + BATCH - 1) / BATCH;

    for (int it = 0; it < niter; ++it) {
        if (t < NBKT) bcnt[t] = 0;
        __syncthreads();

        u32 code[16];
        int rank[16];
        #pragma unroll
        for (int kv = 0; kv < 4; ++kv) {
            int i4 = it * (BATCH / 4) + kv * 256 + t;
            bool v = (i4 * 4) < nE;
            int4 r = v ? r4[i4] : make_int4(0, 0, 0, 0);
            int4 c = v ? c4[i4] : make_int4(0, 0, 0, 0);
            int k0 = kv * 4;
            code[k0 + 0] = v ? (u32)(((r.x >> 5) << 10) | ((r.x & 31) << 5) | (c.x & 31)) : ~0u;
            code[k0 + 1] = v ? (u32)(((r.y >> 5) << 10) | ((r.y & 31) << 5) | (c.y & 31)) : ~0u;
            code[k0 + 2] = v ? (u32)(((r.z >> 5) << 10) | ((r.z & 31) << 5) | (c.z & 31)) : ~0u;
            code[k0 + 3] = v ? (u32)(((r.w >> 5) << 10) | ((r.w & 31) << 5) | (c.w & 31)) : ~0u;
        }
        #pragma unroll
        for (int k = 0; k < 16; ++k)
            rank[k] = (code[k] != ~0u) ? (int)atomicAdd(&bcnt[code[k] >> 16], 1u) : 0;
        __syncthreads();

        u32 v_ = (t < NBKT) ? bcnt[t] : 0;
        u32 s = v_;
        #pragma unroll
        for (int off = 1; off < 64; off <<= 1) {
            u32 u_ = __shfl_up(s, off);
            if ((t & 63) >= off) s += u_;
        }
        if (t == 63) w0tot = s;
        __syncthreads();
        if (t < NBKT) bpos[t] = s - v_ + ((t >= 64) ? w0tot : 0);
        __syncthreads();

        #pragma unroll
        for (int k = 0; k < 16; ++k)
            if (code[k] != ~0u) stage[bpos[code[k] >> 16] + rank[k]] = code[k];
        __syncthreads();

        const int total = (int)(bpos[NBKT - 1] + bcnt[NBKT - 1]);
        for (int j = t; j < total; j += 256) {
            u32 cv = stage[j];
            u32 b = cv >> 16;
            ebuf[cur[b] + (j - bpos[b])] = (u16)cv;   // contiguous per-bucket runs
        }
        __syncthreads();
        if (t < NBKT) cur[t] += bcnt[t];
        __syncthreads();
    }
}

// ===========================================================================
// Pass 4: per-bucket nibble-count adjacency, built in LDS, flushed coalesced
// ===========================================================================
__global__ __launch_bounds__(1024) void countB(
    const u16* __restrict__ ebuf, const u32* __restrict__ bb, u32* __restrict__ adj)
{
    __shared__ u32 nib[8192];   // 64 blocks x 128 words (nibble counts)
    const int t = threadIdx.x, w = blockIdx.x;
    #pragma unroll
    for (int i = t; i < 8192; i += 1024) nib[i] = 0;
    __syncthreads();
    const int s = (int)bb[w], e = (int)bb[w + 1];
    for (int i = s + t; i < e; i += 1024) {
        u32 lc = ebuf[i];
        atomicAdd(&nib[lc >> 3], 1u << ((lc & 7) << 2));
    }
    __syncthreads();
    u32* dst = adj + (size_t)w * 8192;
    #pragma unroll
    for (int i = t; i < 8192; i += 1024) dst[i] = nib[i];
}

// ===========================================================================
// Kernel 5: 4 subgraphs per 256-thread WG (one wave each), MFMA 32x32x16 bf16.
//   A-frag (assumed): row = l&31, k = 16f + 8*(l>>5) + i
//   B-frag (assumed): col = l&31, k = 16f + 8*(l>>5) + i
//   C/D   (verified): col = l&31, row = (q&3) + 8*(q>>2) + 4*(l>>5)
// C->B-frag handoff (M@H result feeding next M@H') is done in REGISTERS:
// lane keeps its column; rows from the other half come via shfl_xor(.,32).
// Only the T@W A-frags (row-major reads) go through small bf16 LDS transposes.
// ===========================================================================
__global__ __launch_bounds__(256, 4) void igmc_kernel(
    const float4* __restrict__ feats4,
    const u32* __restrict__ adj, int NB,
    const float* __restrict__ W1, const float* __restrict__ B1,
    const float* __restrict__ W2, const float* __restrict__ B2,
    const float* __restrict__ W3, const float* __restrict__ B3,
    const float* __restrict__ lin1W, const float* __restrict__ lin1b,
    const float* __restrict__ lin2W, const float* __restrict__ lin2b,
    float* __restrict__ out)
{
    __shared__ u32 raw[4][128];                       // nibble count words
    __shared__ __align__(16) u16 Tb[4][2][32 * 36];   // bf16 transpose buffers
    __shared__ float nsL[4][32];
    __shared__ __align__(16) float4 fst[4][32];       // feats staging
    __shared__ float repL[4][192];

    const int tid = threadIdx.x;
    const int w = tid >> 6, l = tid & 63, h = l >> 5, c = l & 31;
    const int b = blockIdx.x * 4 + w;
    const bool valid = (b < NB);

    // ---- 0) stage raw nibble words + feats ----
    if (valid) {
        uint2 rw = *reinterpret_cast<const uint2*>(adj + (size_t)b * 128 + 2 * l);
        *reinterpret_cast<uint2*>(&raw[w][2 * l]) = rw;
        if (h == 0) fst[w][c] = feats4[(size_t)b * 32 + c];
    }
    __syncthreads();

    // ---- 1) per-lane column counts + in-degree; row sums -> ns ----
    float cf[16];
    int colsum = 0;
    #pragma unroll
    for (int f = 0; f < 2; ++f)
        #pragma unroll
        for (int i = 0; i < 8; ++i) {
            int u = 16 * f + 8 * h + i;
            u32 word = raw[w][u * 4 + (c >> 3)];
            int v = (word >> ((c & 7) << 2)) & 15;
            cf[f * 8 + i] = (float)v;
            colsum += v;
        }
    colsum += __shfl_xor(colsum, 32, 64);             // full in-degree of col c
    const float ndr = rsqrtf(fmaxf((float)colsum, 1.f));

    if (h == 0) {                                     // out-degree of row c
        u32 r0 = raw[w][4 * c], r1 = raw[w][4 * c + 1];
        u32 r2 = raw[w][4 * c + 2], r3 = raw[w][4 * c + 3];
        const u32 m = 0x0F0F0F0Fu;
        u32 bs = (r0 & m) + ((r0 >> 4) & m) + (r1 & m) + ((r1 >> 4) & m)
               + (r2 & m) + ((r2 >> 4) & m) + (r3 & m) + ((r3 >> 4) & m);
        u32 p2 = (bs & 0x00FF00FFu) + ((bs >> 8) & 0x00FF00FFu);
        u32 s = (p2 + (p2 >> 16)) & 0xFFFFu;
        nsL[w][c] = rsqrtf(fmaxf((float)s, 1.f));
    }
    __syncthreads();

    // ---- 2) M A-frags: M[c][u] = A[u][c]*ns[u]*nd[c] ----
    BF8 Mf[2];
    #pragma unroll
    for (int f = 0; f < 2; ++f)
        #pragma unroll
        for (int i = 0; i < 8; ++i) {
            int u = 16 * f + 8 * h + i;
            Mf[f].u[i] = f2bf(cf[f * 8 + i] * nsL[w][u] * ndr);
        }

    // ---- 3) weights ----
    float w1r0 = W1[c], w1r1 = W1[32 + c], w1r2 = W1[64 + c], w1r3 = W1[96 + c];
    const float b1r = B1[c], b2r = B2[c], b3r = B3[c];
    BF8 W2f[2], W3f[2];
    #pragma unroll
    for (int f = 0; f < 2; ++f)
        #pragma unroll
        for (int i = 0; i < 8; ++i) {
            int k = 16 * f + 8 * h + i;
            W2f[f].u[i] = f2bf(W2[k * 32 + c]);
            W3f[f].u[i] = f2bf(W3[k * 32 + c]);
        }

    // ---- 4) H0 = X @ W1 as B-frags ----
    BF8 Xa, Xb;
    #pragma unroll
    for (int f = 0; f < 2; ++f)
        #pragma unroll
        for (int i = 0; i < 8; ++i) {
            int u = 16 * f + 8 * h + i;
            float4 x = fst[w][u];
            u16 val = f2bf(x.x * w1r0 + x.y * w1r1 + x.z * w1r2 + x.w * w1r3);
            if (f == 0) Xa.u[i] = val; else Xb.u[i] = val;
        }

    f32x16 acc;
    float th[16];
    u32 p[8], q[8];

    // helper lambdas (inlined by compiler)
    auto zero_acc = [&]() {
        #pragma unroll
        for (int j = 0; j < 16; ++j) acc[j] = 0.f;
    };
    auto pack_exchange = [&](BF8& Ra, BF8& Rb) {
        #pragma unroll
        for (int j = 0; j < 8; ++j) p[j] = f2bf2(th[2 * j], th[2 * j + 1]);
        #pragma unroll
        for (int j = 0; j < 8; ++j) q[j] = __shfl_xor((int)p[j], 32, 64);
        Ra.w[0] = h ? q[2] : p[0];  Ra.w[1] = h ? q[3] : p[1];
        Ra.w[2] = h ? p[2] : q[0];  Ra.w[3] = h ? p[3] : q[1];
        Rb.w[0] = h ? q[6] : p[4];  Rb.w[1] = h ? q[7] : p[5];
        Rb.w[2] = h ? p[6] : q[4];  Rb.w[3] = h ? p[7] : q[5];
    };

    // ==================== Layer 1: H1 = tanh(M@H0 + b1) ====================
    zero_acc();
    acc = __builtin_amdgcn_mfma_f32_32x32x16_bf16(Mf[0].v, Xa.v, acc, 0, 0, 0);
    acc = __builtin_amdgcn_mfma_f32_32x32x16_bf16(Mf[1].v, Xb.v, acc, 0, 0, 0);
    #pragma unroll
    for (int j = 0; j < 16; ++j) th[j] = tanhf(acc[j] + b1r);
    if (h == 0) { repL[w][c] = th[0]; repL[w][96 + c] = th[8]; }   // rows 0,16
    pack_exchange(Xa, Xb);                     // B-frag of H1, register-only

    // ==================== Layer 2 ====================
    zero_acc();
    acc = __builtin_amdgcn_mfma_f32_32x32x16_bf16(Mf[0].v, Xa.v, acc, 0, 0, 0);
    acc = __builtin_amdgcn_mfma_f32_32x32x16_bf16(Mf[1].v, Xb.v, acc, 0, 0, 0);
    #pragma unroll
    for (int j = 0; j < 16; ++j) {             // T2 -> bf16 transpose buffer
        int r = (j & 3) + 8 * (j >> 2) + 4 * h;
        Tb[w][0][r * 36 + c] = f2bf(acc[j]);
    }
    __syncthreads();
    {
        const u32* t32 = reinterpret_cast<const u32*>(&Tb[w][0][0]);
        int base = 18 * c + 4 * h;
        Xa.w[0] = t32[base];     Xa.w[1] = t32[base + 1];
        Xa.w[2] = t32[base + 2]; Xa.w[3] = t32[base + 3];
        Xb.w[0] = t32[base + 8]; Xb.w[1] = t32[base + 9];
        Xb.w[2] = t32[base + 10]; Xb.w[3] = t32[base + 11];
    }
    zero_acc();
    acc = __builtin_amdgcn_mfma_f32_32x32x16_bf16(Xa.v, W2f[0].v, acc, 0, 0, 0);
    acc = __builtin_amdgcn_mfma_f32_32x32x16_bf16(Xb.v, W2f[1].v, acc, 0, 0, 0);
    #pragma unroll
    for (int j = 0; j < 16; ++j) th[j] = tanhf(acc[j] + b2r);
    if (h == 0) { repL[w][32 + c] = th[0]; repL[w][128 + c] = th[8]; }
    pack_exchange(Xa, Xb);                     // B-frag of H2

    // ==================== Layer 3 ====================
    zero_acc();
    acc = __builtin_amdgcn_mfma_f32_32x32x16_bf16(Mf[0].v, Xa.v, acc, 0, 0, 0);
    acc = __builtin_amdgcn_mfma_f32_32x32x16_bf16(Mf[1].v, Xb.v, acc, 0, 0, 0);
    #pragma unroll
    for (int j = 0; j < 16; ++j) {             // T3 -> transpose buffer #2
        int r = (j & 3) + 8 * (j >> 2) + 4 * h;
        Tb[w][1][r * 36 + c] = f2bf(acc[j]);
    }
    __syncthreads();
    {
        const u32* t32 = reinterpret_cast<const u32*>(&Tb[w][1][0]);
        int base = 18 * c + 4 * h;
        Xa.w[0] = t32[base];     Xa.w[1] = t32[base + 1];
        Xa.w[2] = t32[base + 2]; Xa.w[3] = t32[base + 3];
        Xb.w[0] = t32[base + 8]; Xb.w[1] = t32[base + 9];
        Xb.w[2] = t32[base + 10]; Xb.w[3] = t32[base + 11];
    }
    zero_acc();
    acc = __builtin_amdgcn_mfma_f32_32x32x16_bf16(Xa.v, W3f[0].v, acc, 0, 0, 0);
    acc = __builtin_amdgcn_mfma_f32_32x32x16_bf16(Xb.v, W3f[1].v, acc, 0, 0, 0);
    if (h == 0) {
        repL[w][64 + c]  = tanhf(acc[0] + b3r);   // row 0
        repL[w][160 + c] = tanhf(acc[8] + b3r);   // row 16
    }
    __syncthreads();

    // ==================== Head (fp32 VALU) ====================
    {
        float a = 0.f;
        #pragma unroll 8
        for (int k2 = 0; k2 < 96; ++k2) {
            int k = h * 96 + k2;
            a += repL[w][k] * lin1W[k * 32 + c];
        }
        a += __shfl_xor(a, 32, 64);
        a += lin1b[c];
        float hr = fmaxf(a, 0.f);
        float pp = hr * lin2W[c];
        #pragma unroll
        for (int off = 16; off > 0; off >>= 1) pp += __shfl_xor(pp, off, 64);
        if (l == 0 && valid) out[b] = pp + lin2b[0];
    }
}

// ---- fallback: single-copy nibble adjacency, device atomics (correct, slow) ----
__global__ __launch_bounds__(256) void build_adj(
    const int* __restrict__ row, const int* __restrict__ col,
    u32* __restrict__ adj, int E)
{
    const int gid = blockIdx.x * blockDim.x + threadIdx.x;
    const int stride = gridDim.x * blockDim.x;
    for (int e = gid; e < E; e += stride) {
        int r = row[e], c = col[e];
        int idx = ((r >> 5) << 10) + ((r & 31) << 5) + (c & 31);
        atomicAdd(&adj[idx >> 3], 1u << ((idx & 7) << 2));
    }
}

// ---------------------------------------------------------------------------
extern "C" void kernel_launch(void* const* d_in, const int* in_sizes, int n_in,
                              void* d_out, int out_size, void* d_ws, size_t ws_size,
                              hipStream_t stream)
{
    const float* feats = (const float*)d_in[0];
    const int*   row   = (const int*)d_in[1];
    const int*   col   = (const int*)d_in[2];
    const float* W1    = (const float*)d_in[3];
    const float* b1    = (const float*)d_in[4];
    const float* W2    = (const float*)d_in[5];
    const float* b2    = (const float*)d_in[6];
    const float* W3    = (const float*)d_in[7];
    const float* b3    = (const float*)d_in[8];
    const float* lin1W = (const float*)d_in[9];
    const float* lin1b = (const float*)d_in[10];
    const float* lin2W = (const float*)d_in[11];
    const float* lin2b = (const float*)d_in[12];

    const int N = in_sizes[0] / 4;
    const int E = in_sizes[1];
    const int NB = N / 32;

    const int CH = (((E + GA - 1) / GA) + 3) & ~3;
    const size_t off_hist = 1024;                                  // bb: 129 u32
    const size_t off_ebuf = off_hist + (size_t)GA * NBKT * 4;      // hist 128 KB
    const size_t off_adj  = (off_ebuf + (size_t)E * 2 + 255) & ~(size_t)255;
    const size_t need     = off_adj + (size_t)NB * 512;
    const bool fast = (ws_size >= need) && (NB == 8192) && ((E & 3) == 0);

    if (fast) {
        u32* bb   = (u32*)d_ws;
        u32* hist = (u32*)((char*)d_ws + off_hist);
        u16* ebuf = (u16*)((char*)d_ws + off_ebuf);
        u32* adj  = (u32*)((char*)d_ws + off_adj);
        histA<<<GA, 256, 0, stream>>>(row, hist, E, CH);
        scanA<<<1, 128, 0, stream>>>(hist, bb, E);
        scatterA<<<GA, 256, 0, stream>>>(row, col, hist, ebuf, E, CH);
        countB<<<NBKT, 1024, 0, stream>>>(ebuf, bb, adj);
        igmc_kernel<<<NB / 4, 256, 0, stream>>>(
            reinterpret_cast<const float4*>(feats), adj, NB,
            W1, b1, W2, b2, W3, b3, lin1W, lin1b, lin2W, lin2b,
            (float*)d_out);
    } else {
        u32* adj = (u32*)d_ws;
        hipMemsetAsync(d_ws, 0, (size_t)NB * 512, stream);
        int eblocks = (E + 255) / 256;
        if (eblocks > 2048) eblocks = 2048;
        build_adj<<<eblocks, 256, 0, stream>>>(row, col, adj, E);
        igmc_kernel<<<(NB + 3) / 4, 256, 0, stream>>>(
            reinterpret_cast<const float4*>(feats), adj, NB,
            W1, b1, W2, b2, W3, b3, lin1W, lin1b, lin2W, lin2b,
            (float*)d_out);
    }
}

// Round 7
// 75.281 us; speedup vs baseline: 2.8252x; 1.1039x over previous
//
#include <hip/hip_runtime.h>

typedef __attribute__((ext_vector_type(8))) short bf16x8;
typedef __attribute__((ext_vector_type(16))) float f32x16;
typedef unsigned int u32;
typedef unsigned short u16;

#define GA   1024     // chunks (hist/scatter WGs); 4096 edges each at E=4.2M
#define NBKT 128      // buckets; bucket = 64 consecutive blocks
#define BATCH 4096    // edges per scatter batch (== CH at E=4.2M)

union BF8 { bf16x8 v; u16 u[8]; u32 w[4]; };

static __device__ __forceinline__ u16 f2bf(float f) {
    u32 u = __float_as_uint(f);
    return (u16)((u + 0x7FFFu + ((u >> 16) & 1u)) >> 16);   // RNE
}
static __device__ __forceinline__ u32 f2bf2(float lo, float hi) {
    return (u32)f2bf(lo) | ((u32)f2bf(hi) << 16);
}

// ===========================================================================
// Pass 1: per-chunk histogram of buckets (LDS atomics only)
// ===========================================================================
__global__ __launch_bounds__(256) void histA(
    const int* __restrict__ row, u32* __restrict__ hist, int E, int CH)
{
    __shared__ u32 h[NBKT];
    const int t = threadIdx.x, g = blockIdx.x;
    if (t < NBKT) h[t] = 0;
    __syncthreads();
    const int beg = g * CH, end = min(E, beg + CH);
    const int n4 = (end - beg) >> 2;
    const int4* r4 = reinterpret_cast<const int4*>(row + beg);
    for (int i = t; i < n4; i += 256) {
        int4 r = r4[i];
        atomicAdd(&h[r.x >> 11], 1u);
        atomicAdd(&h[r.y >> 11], 1u);
        atomicAdd(&h[r.z >> 11], 1u);
        atomicAdd(&h[r.w >> 11], 1u);
    }
    __syncthreads();
    if (t < NBKT) hist[g * NBKT + t] = h[t];
}

// ===========================================================================
// Pass 2: per-bucket exclusive scan over chunks.
// WG b: read hist[g][b] (strided L2 reads), scan, write cursor[b][g]
// (coalesced) and tot[b]. No global-scattered WRITES anywhere.
// ===========================================================================
__global__ __launch_bounds__(256) void scanB(
    const u32* __restrict__ hist, u32* __restrict__ cursor, u32* __restrict__ tot)
{
    __shared__ u32 wt[4];
    const int b = blockIdx.x, t = threadIdx.x;
    u32 x[4];
    #pragma unroll
    for (int j = 0; j < 4; ++j) x[j] = hist[(4 * t + j) * NBKT + b];
    const u32 s = x[0] + x[1] + x[2] + x[3];
    u32 inc = s;
    #pragma unroll
    for (int off = 1; off < 64; off <<= 1) {
        u32 u_ = __shfl_up(inc, off, 64);
        if ((t & 63) >= off) inc += u_;
    }
    if ((t & 63) == 63) wt[t >> 6] = inc;
    __syncthreads();
    u32 woff = 0;
    for (int w = 0; w < (t >> 6); ++w) woff += wt[w];
    u32 run = woff + inc - s;            // exclusive over threads
    #pragma unroll
    for (int j = 0; j < 4; ++j) {
        cursor[b * GA + 4 * t + j] = run;
        run += x[j];
    }
    if (t == 255) tot[b] = run;          // bucket total
}

// ===========================================================================
// Pass 3: batched compaction scatter — one batch per WG (GA=1024 -> 4 WG/CU).
// bb (bucket bases) recomputed in-WG via shfl scan of tot (cheap, no extra pass)
// ===========================================================================
__global__ __launch_bounds__(256) void scatterA(
    const int* __restrict__ row, const int* __restrict__ col,
    const u32* __restrict__ cursor, const u32* __restrict__ tot,
    u16* __restrict__ ebuf, int E, int CH)
{
    __shared__ u32 cur[NBKT], bcnt[NBKT], bpos[NBKT];
    __shared__ u32 stage[BATCH];
    __shared__ u32 w0s;
    const int t = threadIdx.x, g = blockIdx.x;

    // ---- bucket base offsets via 128-lane shfl scan of tot ----
    {
        u32 tv = (t < NBKT) ? tot[t] : 0;
        u32 inc = tv;
        #pragma unroll
        for (int off = 1; off < 64; off <<= 1) {
            u32 u_ = __shfl_up(inc, off, 64);
            if ((t & 63) >= off) inc += u_;
        }
        if (t == 63) w0s = inc;
        __syncthreads();
        if (t < NBKT)
            cur[t] = (inc - tv + ((t >= 64) ? w0s : 0)) + cursor[t * GA + g];
    }

    const int beg = g * CH, end = min(E, beg + CH);
    const int nE = end - beg;                       // multiple of 4 (or 0)
    const int4* r4 = reinterpret_cast<const int4*>(row + beg);
    const int4* c4 = reinterpret_cast<const int4*>(col + beg);
    const int niter = (nE + BATCH - 1) / BATCH;

    for (int it = 0; it < niter; ++it) {
        if (t < NBKT) bcnt[t] = 0;
        __syncthreads();

        u32 code[16];
        int rank[16];
        #pragma unroll
        for (int kv = 0; kv < 4; ++kv) {
            int i4 = it * (BATCH / 4) + kv * 256 + t;
            bool v = (i4 * 4) < nE;
            int4 r = v ? r4[i4] : make_int4(0, 0, 0, 0);
            int4 c = v ? c4[i4] : make_int4(0, 0, 0, 0);
            int k0 = kv * 4;
            code[k0 + 0] = v ? (u32)(((r.x >> 5) << 10) | ((r.x & 31) << 5) | (c.x & 31)) : ~0u;
            code[k0 + 1] = v ? (u32)(((r.y >> 5) << 10) | ((r.y & 31) << 5) | (c.y & 31)) : ~0u;
            code[k0 + 2] = v ? (u32)(((r.z >> 5) << 10) | ((r.z & 31) << 5) | (c.z & 31)) : ~0u;
            code[k0 + 3] = v ? (u32)(((r.w >> 5) << 10) | ((r.w & 31) << 5) | (c.w & 31)) : ~0u;
        }
        #pragma unroll
        for (int k = 0; k < 16; ++k)
            rank[k] = (code[k] != ~0u) ? (int)atomicAdd(&bcnt[code[k] >> 16], 1u) : 0;
        __syncthreads();

        u32 v_ = (t < NBKT) ? bcnt[t] : 0;
        u32 s = v_;
        #pragma unroll
        for (int off = 1; off < 64; off <<= 1) {
            u32 u_ = __shfl_up(s, off, 64);
            if ((t & 63) >= off) s += u_;
        }
        if (t == 63) w0s = s;
        __syncthreads();
        if (t < NBKT) bpos[t] = s - v_ + ((t >= 64) ? w0s : 0);
        __syncthreads();

        #pragma unroll
        for (int k = 0; k < 16; ++k)
            if (code[k] != ~0u) stage[bpos[code[k] >> 16] + rank[k]] = code[k];
        __syncthreads();

        const int total = (int)(bpos[NBKT - 1] + bcnt[NBKT - 1]);
        for (int j = t; j < total; j += 256) {
            u32 cv = stage[j];
            u32 b = cv >> 16;
            ebuf[cur[b] + (j - bpos[b])] = (u16)cv;   // contiguous per-bucket runs
        }
        __syncthreads();
        if (t < NBKT) cur[t] += bcnt[t];
        __syncthreads();
    }
}

// ===========================================================================
// Pass 4: half-bucket nibble-count adjacency (256 WGs), built in LDS.
// WG w: bucket = w>>1, keeps edges whose blkLocal bit5 == (w&1); 32 blocks,
// 16 KB nib, coalesced 16 KB flush. bb recomputed via shfl scan of tot.
// ===========================================================================
__global__ __launch_bounds__(512) void countB(
    const u16* __restrict__ ebuf, const u32* __restrict__ tot, u32* __restrict__ adj)
{
    __shared__ u32 nib[4096];    // 32 blocks x 128 words
    __shared__ u32 bbL[NBKT];
    __shared__ u32 w0s;
    const int t = threadIdx.x, w = blockIdx.x;
    const int bucket = w >> 1;
    const u32 half = (u32)(w & 1);

    {
        u32 tv = (t < NBKT) ? tot[t] : 0;
        u32 inc = tv;
        #pragma unroll
        for (int off = 1; off < 64; off <<= 1) {
            u32 u_ = __shfl_up(inc, off, 64);
            if ((t & 63) >= off) inc += u_;
        }
        if (t == 63) w0s = inc;
        __syncthreads();
        if (t < NBKT) bbL[t] = inc - tv + ((t >= 64) ? w0s : 0);
    }
    #pragma unroll
    for (int i = t; i < 4096; i += 512) nib[i] = 0;
    __syncthreads();

    const int s = (int)bbL[bucket];
    const int e = s + (int)tot[bucket];
    for (int i = s + t; i < e; i += 512) {
        u32 lc = ebuf[i];
        if (((lc >> 15) & 1u) == half)
            atomicAdd(&nib[((lc >> 10) & 31) * 128 + ((lc & 1023) >> 3)],
                      1u << ((lc & 7) << 2));
    }
    __syncthreads();
    u32* dst = adj + (size_t)w * 4096;
    #pragma unroll
    for (int i = t; i < 4096; i += 512) dst[i] = nib[i];
}

// ===========================================================================
// Kernel 5: 4 subgraphs per 256-thread WG (one wave each), MFMA 32x32x16 bf16.
//   A-frag (assumed): row = l&31, k = 16f + 8*(l>>5) + i
//   B-frag (assumed): col = l&31, k = 16f + 8*(l>>5) + i
//   C/D   (verified): col = l&31, row = (q&3) + 8*(q>>2) + 4*(l>>5)
// C->B-frag handoffs register-only via shfl_xor(.,32); T@W A-frags via small
// bf16 LDS transposes.
// ===========================================================================
__global__ __launch_bounds__(256, 4) void igmc_kernel(
    const float4* __restrict__ feats4,
    const u32* __restrict__ adj, int NB,
    const float* __restrict__ W1, const float* __restrict__ B1,
    const float* __restrict__ W2, const float* __restrict__ B2,
    const float* __restrict__ W3, const float* __restrict__ B3,
    const float* __restrict__ lin1W, const float* __restrict__ lin1b,
    const float* __restrict__ lin2W, const float* __restrict__ lin2b,
    float* __restrict__ out)
{
    __shared__ u32 raw[4][128];                       // nibble count words
    __shared__ __align__(16) u16 Tb[4][2][32 * 36];   // bf16 transpose buffers
    __shared__ float nsL[4][32];
    __shared__ __align__(16) float4 fst[4][32];       // feats staging
    __shared__ float repL[4][192];

    const int tid = threadIdx.x;
    const int w = tid >> 6, l = tid & 63, h = l >> 5, c = l & 31;
    const int b = blockIdx.x * 4 + w;
    const bool valid = (b < NB);

    if (valid) {
        uint2 rw = *reinterpret_cast<const uint2*>(adj + (size_t)b * 128 + 2 * l);
        *reinterpret_cast<uint2*>(&raw[w][2 * l]) = rw;
        if (h == 0) fst[w][c] = feats4[(size_t)b * 32 + c];
    }
    __syncthreads();

    float cf[16];
    int colsum = 0;
    #pragma unroll
    for (int f = 0; f < 2; ++f)
        #pragma unroll
        for (int i = 0; i < 8; ++i) {
            int u = 16 * f + 8 * h + i;
            u32 word = raw[w][u * 4 + (c >> 3)];
            int v = (word >> ((c & 7) << 2)) & 15;
            cf[f * 8 + i] = (float)v;
            colsum += v;
        }
    colsum += __shfl_xor(colsum, 32, 64);
    const float ndr = rsqrtf(fmaxf((float)colsum, 1.f));

    if (h == 0) {
        u32 r0 = raw[w][4 * c], r1 = raw[w][4 * c + 1];
        u32 r2 = raw[w][4 * c + 2], r3 = raw[w][4 * c + 3];
        const u32 m = 0x0F0F0F0Fu;
        u32 bs = (r0 & m) + ((r0 >> 4) & m) + (r1 & m) + ((r1 >> 4) & m)
               + (r2 & m) + ((r2 >> 4) & m) + (r3 & m) + ((r3 >> 4) & m);
        u32 p2 = (bs & 0x00FF00FFu) + ((bs >> 8) & 0x00FF00FFu);
        u32 s = (p2 + (p2 >> 16)) & 0xFFFFu;
        nsL[w][c] = rsqrtf(fmaxf((float)s, 1.f));
    }
    __syncthreads();

    BF8 Mf[2];
    #pragma unroll
    for (int f = 0; f < 2; ++f)
        #pragma unroll
        for (int i = 0; i < 8; ++i) {
            int u = 16 * f + 8 * h + i;
            Mf[f].u[i] = f2bf(cf[f * 8 + i] * nsL[w][u] * ndr);
        }

    float w1r0 = W1[c], w1r1 = W1[32 + c], w1r2 = W1[64 + c], w1r3 = W1[96 + c];
    const float b1r = B1[c], b2r = B2[c], b3r = B3[c];
    BF8 W2f[2], W3f[2];
    #pragma unroll
    for (int f = 0; f < 2; ++f)
        #pragma unroll
        for (int i = 0; i < 8; ++i) {
            int k = 16 * f + 8 * h + i;
            W2f[f].u[i] = f2bf(W2[k * 32 + c]);
            W3f[f].u[i] = f2bf(W3[k * 32 + c]);
        }

    BF8 Xa, Xb;
    #pragma unroll
    for (int f = 0; f < 2; ++f)
        #pragma unroll
        for (int i = 0; i < 8; ++i) {
            int u = 16 * f + 8 * h + i;
            float4 x = fst[w][u];
            u16 val = f2bf(x.x * w1r0 + x.y * w1r1 + x.z * w1r2 + x.w * w1r3);
            if (f == 0) Xa.u[i] = val; else Xb.u[i] = val;
        }

    f32x16 acc;
    float th[16];
    u32 p[8], q[8];

    auto zero_acc = [&]() {
        #pragma unroll
        for (int j = 0; j < 16; ++j) acc[j] = 0.f;
    };
    auto pack_exchange = [&](BF8& Ra, BF8& Rb) {
        #pragma unroll
        for (int j = 0; j < 8; ++j) p[j] = f2bf2(th[2 * j], th[2 * j + 1]);
        #pragma unroll
        for (int j = 0; j < 8; ++j) q[j] = __shfl_xor((int)p[j], 32, 64);
        Ra.w[0] = h ? q[2] : p[0];  Ra.w[1] = h ? q[3] : p[1];
        Ra.w[2] = h ? p[2] : q[0];  Ra.w[3] = h ? p[3] : q[1];
        Rb.w[0] = h ? q[6] : p[4];  Rb.w[1] = h ? q[7] : p[5];
        Rb.w[2] = h ? p[6] : q[4];  Rb.w[3] = h ? p[7] : q[5];
    };

    // ==================== Layer 1 ====================
    zero_acc();
    acc = __builtin_amdgcn_mfma_f32_32x32x16_bf16(Mf[0].v, Xa.v, acc, 0, 0, 0);
    acc = __builtin_amdgcn_mfma_f32_32x32x16_bf16(Mf[1].v, Xb.v, acc, 0, 0, 0);
    #pragma unroll
    for (int j = 0; j < 16; ++j) th[j] = tanhf(acc[j] + b1r);
    if (h == 0) { repL[w][c] = th[0]; repL[w][96 + c] = th[8]; }
    pack_exchange(Xa, Xb);

    // ==================== Layer 2 ====================
    zero_acc();
    acc = __builtin_amdgcn_mfma_f32_32x32x16_bf16(Mf[0].v, Xa.v, acc, 0, 0, 0);
    acc = __builtin_amdgcn_mfma_f32_32x32x16_bf16(Mf[1].v, Xb.v, acc, 0, 0, 0);
    #pragma unroll
    for (int j = 0; j < 16; ++j) {
        int r = (j & 3) + 8 * (j >> 2) + 4 * h;
        Tb[w][0][r * 36 + c] = f2bf(acc[j]);
    }
    __syncthreads();
    {
        const u32* t32 = reinterpret_cast<const u32*>(&Tb[w][0][0]);
        int base = 18 * c + 4 * h;
        Xa.w[0] = t32[base];     Xa.w[1] = t32[base + 1];
        Xa.w[2] = t32[base + 2]; Xa.w[3] = t32[base + 3];
        Xb.w[0] = t32[base + 8]; Xb.w[1] = t32[base + 9];
        Xb.w[2] = t32[base + 10]; Xb.w[3] = t32[base + 11];
    }
    zero_acc();
    acc = __builtin_amdgcn_mfma_f32_32x32x16_bf16(Xa.v, W2f[0].v, acc, 0, 0, 0);
    acc = __builtin_amdgcn_mfma_f32_32x32x16_bf16(Xb.v, W2f[1].v, acc, 0, 0, 0);
    #pragma unroll
    for (int j = 0; j < 16; ++j) th[j] = tanhf(acc[j] + b2r);
    if (h == 0) { repL[w][32 + c] = th[0]; repL[w][128 + c] = th[8]; }
    pack_exchange(Xa, Xb);

    // ==================== Layer 3 ====================
    zero_acc();
    acc = __builtin_amdgcn_mfma_f32_32x32x16_bf16(Mf[0].v, Xa.v, acc, 0, 0, 0);
    acc = __builtin_amdgcn_mfma_f32_32x32x16_bf16(Mf[1].v, Xb.v, acc, 0, 0, 0);
    #pragma unroll
    for (int j = 0; j < 16; ++j) {
        int r = (j & 3) + 8 * (j >> 2) + 4 * h;
        Tb[w][1][r * 36 + c] = f2bf(acc[j]);
    }
    __syncthreads();
    {
        const u32* t32 = reinterpret_cast<const u32*>(&Tb[w][1][0]);
        int base = 18 * c + 4 * h;
        Xa.w[0] = t32[base];     Xa.w[1] = t32[base + 1];
        Xa.w[2] = t32[base + 2]; Xa.w[3] = t32[base + 3];
        Xb.w[0] = t32[base + 8]; Xb.w[1] = t32[base + 9];
        Xb.w[2] = t32[base + 10]; Xb.w[3] = t32[base + 11];
    }
    zero_acc();
    acc = __builtin_amdgcn_mfma_f32_32x32x16_bf16(Xa.v, W3f[0].v, acc, 0, 0, 0);
    acc = __builtin_amdgcn_mfma_f32_32x32x16_bf16(Xb.v, W3f[1].v, acc, 0, 0, 0);
    if (h == 0) {
        repL[w][64 + c]  = tanhf(acc[0] + b3r);
        repL[w][160 + c] = tanhf(acc[8] + b3r);
    }
    __syncthreads();

    // ==================== Head ====================
    {
        float a = 0.f;
        #pragma unroll 8
        for (int k2 = 0; k2 < 96; ++k2) {
            int k = h * 96 + k2;
            a += repL[w][k] * lin1W[k * 32 + c];
        }
        a += __shfl_xor(a, 32, 64);
        a += lin1b[c];
        float hr = fmaxf(a, 0.f);
        float pp = hr * lin2W[c];
        #pragma unroll
        for (int off = 16; off > 0; off >>= 1) pp += __shfl_xor(pp, off, 64);
        if (l == 0 && valid) out[b] = pp + lin2b[0];
    }
}

// ---- fallback: single-copy nibble adjacency, device atomics (correct, slow) ----
__global__ __launch_bounds__(256) void build_adj(
    const int* __restrict__ row, const int* __restrict__ col,
    u32* __restrict__ adj, int E)
{
    const int gid = blockIdx.x * blockDim.x + threadIdx.x;
    const int stride = gridDim.x * blockDim.x;
    for (int e = gid; e < E; e += stride) {
        int r = row[e], c = col[e];
        int idx = ((r >> 5) << 10) + ((r & 31) << 5) + (c & 31);
        atomicAdd(&adj[idx >> 3], 1u << ((idx & 7) << 2));
    }
}

// ---------------------------------------------------------------------------
extern "C" void kernel_launch(void* const* d_in, const int* in_sizes, int n_in,
                              void* d_out, int out_size, void* d_ws, size_t ws_size,
                              hipStream_t stream)
{
    const float* feats = (const float*)d_in[0];
    const int*   row   = (const int*)d_in[1];
    const int*   col   = (const int*)d_in[2];
    const float* W1    = (const float*)d_in[3];
    const float* b1    = (const float*)d_in[4];
    const float* W2    = (const float*)d_in[5];
    const float* b2    = (const float*)d_in[6];
    const float* W3    = (const float*)d_in[7];
    const float* b3    = (const float*)d_in[8];
    const float* lin1W = (const float*)d_in[9];
    const float* lin1b = (const float*)d_in[10];
    const float* lin2W = (const float*)d_in[11];
    const float* lin2b = (const float*)d_in[12];

    const int N = in_sizes[0] / 4;
    const int E = in_sizes[1];
    const int NB = N / 32;

    const int CH = (((E + GA - 1) / GA) + 3) & ~3;
    const size_t off_tot    = 0;                                     // 128 u32
    const size_t off_hist   = 1024;
    const size_t off_cursor = off_hist + (size_t)GA * NBKT * 4;      // 512 KB
    const size_t off_ebuf   = off_cursor + (size_t)NBKT * GA * 4;    // 512 KB
    const size_t off_adj    = (off_ebuf + (size_t)E * 2 + 255) & ~(size_t)255;
    const size_t need       = off_adj + (size_t)NB * 512;
    const bool fast = (ws_size >= need) && (NB == 8192) && ((E & 3) == 0)
                      && ((size_t)GA * CH >= (size_t)E);

    if (fast) {
        u32* tot    = (u32*)((char*)d_ws + off_tot);
        u32* hist   = (u32*)((char*)d_ws + off_hist);
        u32* cursor = (u32*)((char*)d_ws + off_cursor);
        u16* ebuf   = (u16*)((char*)d_ws + off_ebuf);
        u32* adj    = (u32*)((char*)d_ws + off_adj);
        histA<<<GA, 256, 0, stream>>>(row, hist, E, CH);
        scanB<<<NBKT, 256, 0, stream>>>(hist, cursor, tot);
        scatterA<<<GA, 256, 0, stream>>>(row, col, cursor, tot, ebuf, E, CH);
        countB<<<2 * NBKT, 512, 0, stream>>>(ebuf, tot, adj);
        igmc_kernel<<<NB / 4, 256, 0, stream>>>(
            reinterpret_cast<const float4*>(feats), adj, NB,
            W1, b1, W2, b2, W3, b3, lin1W, lin1b, lin2W, lin2b,
            (float*)d_out);
    } else {
        u32* adj = (u32*)d_ws;
        hipMemsetAsync(d_ws, 0, (size_t)NB * 512, stream);
        int eblocks = (E + 255) / 256;
        if (eblocks > 2048) eblocks = 2048;
        build_adj<<<eblocks, 256, 0, stream>>>(row, col, adj, E);
        igmc_kernel<<<(NB + 3) / 4, 256, 0, stream>>>(
            reinterpret_cast<const float4*>(feats), adj, NB,
            W1, b1, W2, b2, W3, b3, lin1W, lin1b, lin2W, lin2b,
            (float*)d_out);
    }
}